// Round 8
// baseline (576.502 us; speedup 1.0000x reference)
//
#include <hip/hip_runtime.h>

#define NN 100000   // nodes
#define NF 128      // input features
#define D  64       // hidden dim
#define NE 1600000  // edges
#define NZ 1000000  // hypergraph incidences
#define NH 50000    // hyperedges

#define NS (NN + NH + NN)          // 250000 concatenated id space
#define TOT (NE + 2 * NZ)          // 3600000 adjacency entries
#define NBUK 977                   // ceil(NS/256) buckets of 256 ids
#define NWG1 256                   // phase-1 workgroups
#define P2CAP 6144                 // max entries per bucket

static __device__ __forceinline__ float waveReduceSum(float v) {
#pragma unroll
  for (int off = 32; off > 0; off >>= 1) v += __shfl_down(v, off);
  return v;
}

// Wave-uniform broadcast via readlane (VALU pipe) — used in GEMMs only.
static __device__ __forceinline__ float bcastf(float v, int l) {
  return __int_as_float(__builtin_amdgcn_readlane(__float_as_int(v), l));
}

// ---------------------------------------------------------------------------
// sv[0:64)   u    = conv2_W @ v1          (v1 = lp_W[:64] @ head_W)
// sv[64:128) w2v  = cls_W  @ v2           (v2 = lp_W[64:] @ head_W)
// sv[128]    c_all= lp_b.head_W + head_b + conv2_b.v1 + cls_b.v2
// ---------------------------------------------------------------------------
__global__ void k_vecs(const float* __restrict__ conv2_W, const float* __restrict__ conv2_b,
                       const float* __restrict__ cls_W, const float* __restrict__ cls_b,
                       const float* __restrict__ lp_W, const float* __restrict__ lp_b,
                       const float* __restrict__ head_W, const float* __restrict__ head_b,
                       float* __restrict__ sv) {
  int t = threadIdx.x;  // 0..63, one wave
  __shared__ float v1[64], v2[64];
  float a1 = 0.f, a2 = 0.f;
  for (int c = 0; c < 64; ++c) {
    float hw = head_W[c];
    a1 = fmaf(lp_W[t * 64 + c], hw, a1);
    a2 = fmaf(lp_W[(64 + t) * 64 + c], hw, a2);
  }
  v1[t] = a1;
  v2[t] = a2;
  __syncthreads();
  float u = 0.f, w = 0.f;
  for (int c = 0; c < 64; ++c) {
    u = fmaf(conv2_W[t * 64 + c], v1[c], u);
    w = fmaf(cls_W[t * 64 + c], v2[c], w);
  }
  sv[t] = u;
  sv[64 + t] = w;
  float part = lp_b[t] * head_W[t] + conv2_b[t] * v1[t] + cls_b[t] * v2[t];
  part = waveReduceSum(part);
  if (t == 0) sv[128] = part + head_b[0];
}

// ---------------------------------------------------------------------------
// Tall-skinny GEMM: out[r,c] = scale?*(act(in[r,:K] @ W[K,64] + b[c]))
// readlane broadcast (VALU) + next-row prefetch.
// ---------------------------------------------------------------------------
template <int K, bool BIAS, bool RELU, bool SCALE>
__global__ __launch_bounds__(256) void k_gemm(const float* __restrict__ in,
                                              const float* __restrict__ W,
                                              const float* __restrict__ bias,
                                              const float* __restrict__ scale,
                                              float* __restrict__ out, int nrows) {
  int lane = threadIdx.x & 63;
  int wave = threadIdx.x >> 6;
  float w[K];
#pragma unroll
  for (int k = 0; k < K; ++k) w[k] = W[k * 64 + lane];
  float b = BIAS ? bias[lane] : 0.0f;
  int wid = blockIdx.x * 4 + wave;
  int nw = gridDim.x * 4;
  if (wid >= nrows) return;
  float v0 = in[(size_t)wid * K + lane];
  float v1 = 0.f;
  if constexpr (K == 128) v1 = in[(size_t)wid * K + 64 + lane];
  for (int row = wid; row < nrows; row += nw) {
    int nrow = row + nw;
    float nv0 = 0.f, nv1 = 0.f;
    if (nrow < nrows) {
      nv0 = in[(size_t)nrow * K + lane];
      if constexpr (K == 128) nv1 = in[(size_t)nrow * K + 64 + lane];
    }
    float acc0 = b, acc1 = 0.f;
#pragma unroll
    for (int k = 0; k < 64; k += 2) {
      acc0 = fmaf(bcastf(v0, k), w[k], acc0);
      acc1 = fmaf(bcastf(v0, k + 1), w[k + 1], acc1);
    }
    if constexpr (K == 128) {
#pragma unroll
      for (int k = 0; k < 64; k += 2) {
        acc0 = fmaf(bcastf(v1, k), w[64 + k], acc0);
        acc1 = fmaf(bcastf(v1, k + 1), w[64 + k + 1], acc1);
      }
    }
    float r = acc0 + acc1;
    if (RELU) r = fmaxf(r, 0.0f);
    if (SCALE) r *= scale[row];
    out[(size_t)row * 64 + lane] = r;
    v0 = nv0;
    v1 = nv1;
  }
}

// ---------------------------------------------------------------------------
// CSR build: LDS-binned counting sort.
// ---------------------------------------------------------------------------
__global__ __launch_bounds__(256) void k_ccount(const int* __restrict__ dst,
                                                const int* __restrict__ he,
                                                const int* __restrict__ hv,
                                                int* __restrict__ gcnt) {
  __shared__ int hist[NBUK];
  for (int b = threadIdx.x; b < NBUK; b += 256) hist[b] = 0;
  __syncthreads();
  int step = gridDim.x * 256;
  for (int j = blockIdx.x * 256 + threadIdx.x; j < TOT; j += step) {
    int id;
    if (j < NE) id = dst[j];
    else if (j < NE + NZ) id = NN + he[j - NE];
    else id = NN + NH + hv[j - NE - NZ];
    atomicAdd(&hist[id >> 8], 1);
  }
  __syncthreads();
  for (int b = threadIdx.x; b < NBUK; b += 256) {
    int c = hist[b];
    if (c) atomicAdd(&gcnt[b], c);
  }
}

__global__ __launch_bounds__(1024) void k_cscan(const int* __restrict__ gcnt,
                                                int* __restrict__ gbase,
                                                int* __restrict__ gcur) {
  __shared__ int sh[1024];
  int t = threadIdx.x;
  int v = (t < NBUK) ? gcnt[t] : 0;
  sh[t] = v;
  __syncthreads();
#pragma unroll
  for (int d = 1; d < 1024; d <<= 1) {
    int x = (t >= d) ? sh[t - d] : 0;
    __syncthreads();
    sh[t] += x;
    __syncthreads();
  }
  int excl = sh[t] - v;
  if (t < NBUK) {
    gbase[t] = excl;
    gcur[t] = excl;
  }
  if (t == 1023) gbase[NBUK] = sh[1023];
}

__global__ __launch_bounds__(1024) void k_phase1(const int* __restrict__ src,
                                                 const int* __restrict__ dst,
                                                 const int* __restrict__ he,
                                                 const int* __restrict__ hv,
                                                 int* __restrict__ gcur,
                                                 int* __restrict__ adj) {
  __shared__ int cnt[NBUK], base[NBUK], cur[NBUK];
  int tid = threadIdx.x;
  for (int b = tid; b < NBUK; b += 1024) { cnt[b] = 0; cur[b] = 0; }
  __syncthreads();
  int per = (TOT + NWG1 - 1) / NWG1;
  int s0 = blockIdx.x * per;
  int s1 = s0 + per; if (s1 > TOT) s1 = TOT;
  for (int j = s0 + tid; j < s1; j += 1024) {
    int id;
    if (j < NE) id = dst[j];
    else if (j < NE + NZ) id = NN + he[j - NE];
    else id = NN + NH + hv[j - NE - NZ];
    atomicAdd(&cnt[id >> 8], 1);
  }
  __syncthreads();
  for (int b = tid; b < NBUK; b += 1024) {
    int c = cnt[b];
    if (c) base[b] = atomicAdd(&gcur[b], c);
  }
  __syncthreads();
  for (int j = s0 + tid; j < s1; j += 1024) {
    int id, val;
    if (j < NE)           { id = dst[j];                val = src[j]; }
    else if (j < NE + NZ) { id = NN + he[j - NE];       val = hv[j - NE]; }
    else                  { id = NN + NH + hv[j - NE - NZ]; val = he[j - NE - NZ]; }
    int b = id >> 8;
    int slot = base[b] + atomicAdd(&cur[b], 1);
    adj[slot] = ((id & 255) << 17) | val;   // val < 131072
  }
}

__global__ __launch_bounds__(256) void k_phase2(const int* __restrict__ gbase,
                                                int* __restrict__ adj,
                                                int* __restrict__ off) {
  __shared__ int ent[P2CAP];
  __shared__ int hist[256];
  int b = blockIdx.x, tid = threadIdx.x;
  int s = gbase[b];
  int n = gbase[b + 1] - s;
  if (n > P2CAP) n = P2CAP;  // safety; cannot trigger on this dataset
  hist[tid] = 0;
  __syncthreads();
  for (int k = tid; k < n; k += 256) {
    int v = adj[s + k];
    ent[k] = v;
    atomicAdd(&hist[v >> 17], 1);
  }
  __syncthreads();
  int c = hist[tid];
#pragma unroll
  for (int d = 1; d < 256; d <<= 1) {
    int x = (tid >= d) ? hist[tid - d] : 0;
    __syncthreads();
    hist[tid] += x;
    __syncthreads();
  }
  int excl = hist[tid] - c;
  hist[tid] = excl;
  int gid = (b << 8) + tid;
  if (gid <= NS) off[gid] = s + excl;
  __syncthreads();
  for (int k = tid; k < n; k += 256) {
    int v = ent[k];
    int pos = atomicAdd(&hist[v >> 17], 1);
    adj[s + pos] = v & 0x1FFFF;   // store bare value
  }
}

__global__ void k_dinv(const int* __restrict__ off, float* __restrict__ dinv) {
  int i = blockIdx.x * 256 + threadIdx.x;
  if (i < NN) dinv[i] = rsqrtf((float)(off[i + 1] - off[i] + 1));  // +1 self-loop
}

// ---------------------------------------------------------------------------
// Batched row-gather accumulate: 16 independent 256B loads in flight.
// shfl index broadcast; uses `beg`, `end`, `adj`, `lane` from scope.
// ---------------------------------------------------------------------------
#define GATHER_ROWS16(ROWS, ACCUM_STMT)                                 \
  for (int j0 = beg; j0 < end; j0 += 64) {                              \
    int m = end - j0; if (m > 64) m = 64;                               \
    int av_ = (lane < m) ? adj[j0 + lane] : 0;                          \
    int k = 0;                                                          \
    for (; k + 16 <= m; k += 16) {                                      \
      int s_[16]; float r_[16];                                         \
      _Pragma("unroll")                                                 \
      for (int q = 0; q < 16; ++q) s_[q] = __shfl(av_, k + q);          \
      _Pragma("unroll")                                                 \
      for (int q = 0; q < 16; ++q) r_[q] = ROWS[(size_t)s_[q] * 64 + lane]; \
      _Pragma("unroll")                                                 \
      for (int q = 0; q < 16; ++q) { ACCUM_STMT(r_[q]); }               \
    }                                                                   \
    for (; k < m; ++k) {                                                \
      float r0_ = ROWS[(size_t)__shfl(av_, k) * 64 + lane];             \
      ACCUM_STMT(r0_);                                                  \
    }                                                                   \
  }

// ---------------------------------------------------------------------------
// conv1 gather (xw1p pre-scaled by dinv[row]):
//   t'[i] = dinv[i] * ( relu( dinv[i]*(sum_s xw1p[s] + xw1p[i]) + conv1_b ) . u )
// No weight arrays -> low VGPR -> 16 loads genuinely in flight.
// ---------------------------------------------------------------------------
__global__ __launch_bounds__(256) void k_gcn1_gather(const int* __restrict__ off,
                                                     const int* __restrict__ adj,
                                                     const float* __restrict__ xw1p,
                                                     const float* __restrict__ dinv,
                                                     const float* __restrict__ conv1_b,
                                                     const float* __restrict__ sv,
                                                     float* __restrict__ tp) {
  int i = blockIdx.x * 4 + (threadIdx.x >> 6);
  if (i >= NN) return;
  int lane = threadIdx.x & 63;
  int beg = off[i], end = off[i + 1];
  float acc = 0.f;
#define ACC_ADD(r) acc += (r)
  GATHER_ROWS16(xw1p, ACC_ADD)
#undef ACC_ADD
  float di = dinv[i];
  float r = fmaxf(fmaf(acc + xw1p[(size_t)i * 64 + lane], di, conv1_b[lane]), 0.f);
  float p = waveReduceSum(r * sv[lane]);
  if (lane == 0) tp[i] = p * di;
}

// ---------------------------------------------------------------------------
// Xe gather + matvec. One wave handles 16 hyperedges:
// phase A: mean rows -> per-wave LDS (16-deep gather).
// phase B: B[e,:] = m @ W2[64:,:] + b2, hp read as uniform float4 ds_read_b128,
//          W2 streamed from L1 (amortized over 16 edges). No VGPR weight array.
// ---------------------------------------------------------------------------
__global__ __launch_bounds__(256) void k_xe_gather(const int* __restrict__ off,
                                                   const int* __restrict__ adj,
                                                   const float* __restrict__ C,
                                                   const float* __restrict__ W2,
                                                   const float* __restrict__ b2,
                                                   float* __restrict__ B) {
  __shared__ float hp[4][16][64];
  int lane = threadIdx.x & 63, wv = threadIdx.x >> 6;
  int base = (blockIdx.x * 4 + wv) * 16;
  if (base >= NH) return;
  int ncnt = NH - base; if (ncnt > 16) ncnt = 16;
  for (int n = 0; n < ncnt; ++n) {
    int e = base + n;
    int beg = off[NN + e], end = off[NN + e + 1];
    float acc = 0.f;
#define ACC_ADD(r) acc += (r)
    GATHER_ROWS16(C, ACC_ADD)
#undef ACC_ADD
    hp[wv][n][lane] = acc / fmaxf((float)(end - beg), 1.0f);
  }
  float bb = b2[lane];
  float acc[16];
#pragma unroll
  for (int n = 0; n < 16; ++n) acc[n] = bb;
  const float4* hp4 = (const float4*)&hp[wv][0][0];  // [16][16]
#pragma unroll 4
  for (int k4 = 0; k4 < 16; ++k4) {
    float w0 = W2[(64 + k4 * 4 + 0) * 64 + lane];
    float w1 = W2[(64 + k4 * 4 + 1) * 64 + lane];
    float w2 = W2[(64 + k4 * 4 + 2) * 64 + lane];
    float w3 = W2[(64 + k4 * 4 + 3) * 64 + lane];
#pragma unroll
    for (int n = 0; n < 16; ++n) {
      float4 hv4 = hp4[n * 16 + k4];
      acc[n] = fmaf(hv4.x, w0, acc[n]);
      acc[n] = fmaf(hv4.y, w1, acc[n]);
      acc[n] = fmaf(hv4.z, w2, acc[n]);
      acc[n] = fmaf(hv4.w, w3, acc[n]);
    }
  }
#pragma unroll
  for (int n = 0; n < 16; ++n)
    if (n < ncnt) B[(size_t)(base + n) * 64 + lane] = acc[n];
}

// ---------------------------------------------------------------------------
// Final fused kernel. One wave handles 16 nodes:
// phase A (per node): xv-gather over hv-CSR (16-deep) -> hpre row into LDS;
//                     gcn2 scalar gather -> per-node scalar into LDS.
// phase B: batched hfin = relu(hpre@Wu+bu) with uniform float4 hp reads;
//          out = hfin.w2v + scalar.
// ---------------------------------------------------------------------------
__global__ __launch_bounds__(256) void k_final(const int* __restrict__ off,
                                               const int* __restrict__ adj,
                                               const float* __restrict__ A,
                                               const float* __restrict__ B,
                                               const float* __restrict__ h,
                                               const float* __restrict__ tp,
                                               const float* __restrict__ dinv,
                                               const float* __restrict__ Wu,
                                               const float* __restrict__ bu,
                                               const float* __restrict__ sv,
                                               float* __restrict__ out) {
  __shared__ float hp[4][16][64];
  __shared__ float sarr[4][16];
  int lane = threadIdx.x & 63, wv = threadIdx.x >> 6;
  int base = (blockIdx.x * 4 + wv) * 16;
  if (base >= NN) return;
  int ncnt = NN - base; if (ncnt > 16) ncnt = 16;
  float c_all = sv[128];
  for (int n = 0; n < ncnt; ++n) {
    int i = base + n;
    float av = A[(size_t)i * 64 + lane];
    int beg = off[NN + NH + i], end = off[NN + NH + i + 1];
    float accm = 0.f;
#define ACC_RELU(r) accm += fmaxf(av + (r), 0.f)
    GATHER_ROWS16(B, ACC_RELU)
#undef ACC_RELU
    hp[wv][n][lane] = accm * (0.5f / fmaxf((float)(end - beg), 1.0f)) +
                      0.5f * h[(size_t)i * 64 + lane];
    // gcn2 scalar gather over dst-CSR
    float di = dinv[i];
    int db = off[i], de = off[i + 1];
    float g = 0.f;
    for (int j = db + lane; j < de; j += 64) g += tp[adj[j]];
    float gr = waveReduceSum(g);
    if (lane == 0) sarr[wv][n] = gr * di + tp[i] * di + c_all;
  }
  float bb = bu[lane];
  float w2v = sv[64 + lane];
  float acc[16];
#pragma unroll
  for (int n = 0; n < 16; ++n) acc[n] = bb;
  const float4* hp4 = (const float4*)&hp[wv][0][0];  // [16][16]
#pragma unroll 4
  for (int k4 = 0; k4 < 16; ++k4) {
    float w0 = Wu[(k4 * 4 + 0) * 64 + lane];
    float w1 = Wu[(k4 * 4 + 1) * 64 + lane];
    float w2 = Wu[(k4 * 4 + 2) * 64 + lane];
    float w3 = Wu[(k4 * 4 + 3) * 64 + lane];
#pragma unroll
    for (int n = 0; n < 16; ++n) {
      float4 hv4 = hp4[n * 16 + k4];
      acc[n] = fmaf(hv4.x, w0, acc[n]);
      acc[n] = fmaf(hv4.y, w1, acc[n]);
      acc[n] = fmaf(hv4.z, w2, acc[n]);
      acc[n] = fmaf(hv4.w, w3, acc[n]);
    }
  }
#pragma unroll
  for (int n = 0; n < 16; ++n) {
    if (n < ncnt) {
      float part = fmaxf(acc[n], 0.f) * w2v;
      float tot = waveReduceSum(part);
      if (lane == 0) out[base + n] = tot + sarr[wv][n];
    }
  }
}

// ---------------------------------------------------------------------------
extern "C" void kernel_launch(void* const* d_in, const int* in_sizes, int n_in,
                              void* d_out, int out_size, void* d_ws, size_t ws_size,
                              hipStream_t stream) {
  (void)in_sizes; (void)n_in; (void)out_size; (void)ws_size;
  const float* x       = (const float*)d_in[0];
  const int*   ei      = (const int*)d_in[1];
  const int*   hv      = (const int*)d_in[2];
  const int*   he      = (const int*)d_in[3];
  const float* conv1_W = (const float*)d_in[5];
  const float* conv1_b = (const float*)d_in[6];
  const float* conv2_W = (const float*)d_in[7];
  const float* conv2_b = (const float*)d_in[8];
  const float* lin_W   = (const float*)d_in[9];
  const float* lin_b   = (const float*)d_in[10];
  const float* W1      = (const float*)d_in[11];
  const float* b1      = (const float*)d_in[12];
  const float* W2      = (const float*)d_in[13];
  const float* b2      = (const float*)d_in[14];
  const float* Wu      = (const float*)d_in[15];
  const float* bu      = (const float*)d_in[16];
  const float* cls_W   = (const float*)d_in[17];
  const float* cls_b   = (const float*)d_in[18];
  const float* lp_W    = (const float*)d_in[19];
  const float* lp_b    = (const float*)d_in[20];
  const float* head_W  = (const float*)d_in[21];
  const float* head_b  = (const float*)d_in[22];
  const int* src = ei;
  const int* dst = ei + NE;
  float* out = (float*)d_out;

  // workspace (4B units). Aliasing: P = xw1' -> C.
  float* H     = (float*)d_ws;             // N*64
  float* P     = H + (size_t)NN * 64;      // N*64   xw1' then C
  float* Q     = P + (size_t)NN * 64;      // N*64   A
  float* XE    = Q + (size_t)NN * 64;      // NH*64  B
  float* DINV  = XE + (size_t)NH * 64;     // N
  float* TP    = DINV + NN;                // N   t' = t*dinv
  float* SV    = TP + NN;                  // 192
  int* GCNT    = (int*)(SV + 192);         // NBUK
  int* GBASE   = GCNT + NBUK;              // NBUK+1
  int* GCUR    = GBASE + NBUK + 1;         // NBUK
  int* OFF     = GCUR + NBUK;              // NS+1
  int* ADJ     = OFF + NS + 1;             // TOT
  // total ~95 MiB

  hipMemsetAsync(GCNT, 0, NBUK * 4, stream);

  k_vecs<<<1, 64, 0, stream>>>(conv2_W, conv2_b, cls_W, cls_b, lp_W, lp_b, head_W, head_b, SV);

  // CSR build (LDS-binned counting sort)
  k_ccount<<<512, 256, 0, stream>>>(dst, he, hv, GCNT);
  k_cscan<<<1, 1024, 0, stream>>>(GCNT, GBASE, GCUR);
  k_phase1<<<NWG1, 1024, 0, stream>>>(src, dst, he, hv, GCUR, ADJ);
  k_phase2<<<NBUK, 256, 0, stream>>>(GBASE, ADJ, OFF);
  k_dinv<<<(NN + 255) / 256, 256, 0, stream>>>(OFF, DINV);

  // dense: xw1' = (x @ conv1_W) * dinv[row]; h = relu(x @ lin_W + lin_b)
  k_gemm<128, false, false, true><<<2048, 256, 0, stream>>>(x, conv1_W, nullptr, DINV, P, NN);
  k_gemm<128, true, true, false><<<2048, 256, 0, stream>>>(x, lin_W, lin_b, nullptr, H, NN);

  // GCN branch collapsed to t' (conv2 folded into k_final)
  k_gcn1_gather<<<NN / 4, 256, 0, stream>>>(OFF, ADJ, P, DINV, conv1_b, SV, TP);

  // hyper branch dense parts: A = h @ W2[:64] (Q), C = h @ W1 + b1 (P)
  k_gemm<64, false, false, false><<<2048, 256, 0, stream>>>(H, W2, nullptr, nullptr, Q, NN);
  k_gemm<64, true, false, false><<<2048, 256, 0, stream>>>(H, W1, b1, nullptr, P, NN);

  // 16 hyperedges per wave -> 3125 waves -> 782 blocks
  k_xe_gather<<<782, 256, 0, stream>>>(OFF, ADJ, P, W2, b2, XE);

  // 16 nodes per wave -> 6250 waves -> 1563 blocks
  k_final<<<1563, 256, 0, stream>>>(OFF, ADJ, Q, XE, H, TP, DINV, Wu, bu, SV, out);
}

// Round 9
// 497.052 us; speedup vs baseline: 1.1598x; 1.1598x over previous
//
#include <hip/hip_runtime.h>

#define NN 100000   // nodes
#define NF 128      // input features
#define D  64       // hidden dim
#define NE 1600000  // edges
#define NZ 1000000  // hypergraph incidences
#define NH 50000    // hyperedges

#define NS (NN + NH + NN)          // 250000 concatenated id space
#define TOT (NE + 2 * NZ)          // 3600000 adjacency entries
#define NBUK 977                   // ceil(NS/256) buckets of 256 ids
#define NWG1 256                   // phase-1 workgroups
#define P2CAP 6144                 // max entries per bucket

static __device__ __forceinline__ float waveReduceSum(float v) {
#pragma unroll
  for (int off = 32; off > 0; off >>= 1) v += __shfl_down(v, off);
  return v;
}

// Wave-uniform broadcast via readlane (VALU pipe) — used in GEMMs only.
static __device__ __forceinline__ float bcastf(float v, int l) {
  return __int_as_float(__builtin_amdgcn_readlane(__float_as_int(v), l));
}

// ---------------------------------------------------------------------------
// sv[0:64)   u    = conv2_W @ v1          (v1 = lp_W[:64] @ head_W)
// sv[64:128) w2v  = cls_W  @ v2           (v2 = lp_W[64:] @ head_W)
// sv[128]    c_all= lp_b.head_W + head_b + conv2_b.v1 + cls_b.v2
// ---------------------------------------------------------------------------
__global__ void k_vecs(const float* __restrict__ conv2_W, const float* __restrict__ conv2_b,
                       const float* __restrict__ cls_W, const float* __restrict__ cls_b,
                       const float* __restrict__ lp_W, const float* __restrict__ lp_b,
                       const float* __restrict__ head_W, const float* __restrict__ head_b,
                       float* __restrict__ sv) {
  int t = threadIdx.x;  // 0..63, one wave
  __shared__ float v1[64], v2[64];
  float a1 = 0.f, a2 = 0.f;
  for (int c = 0; c < 64; ++c) {
    float hw = head_W[c];
    a1 = fmaf(lp_W[t * 64 + c], hw, a1);
    a2 = fmaf(lp_W[(64 + t) * 64 + c], hw, a2);
  }
  v1[t] = a1;
  v2[t] = a2;
  __syncthreads();
  float u = 0.f, w = 0.f;
  for (int c = 0; c < 64; ++c) {
    u = fmaf(conv2_W[t * 64 + c], v1[c], u);
    w = fmaf(cls_W[t * 64 + c], v2[c], w);
  }
  sv[t] = u;
  sv[64 + t] = w;
  float part = lp_b[t] * head_W[t] + conv2_b[t] * v1[t] + cls_b[t] * v2[t];
  part = waveReduceSum(part);
  if (t == 0) sv[128] = part + head_b[0];
}

// ---------------------------------------------------------------------------
// Tall-skinny GEMM: out[r,c] = scale?*(act(in[r,:K] @ W[K,64] + b[c]))
// readlane broadcast (VALU) + next-row prefetch.  [R7-proven: fast]
// ---------------------------------------------------------------------------
template <int K, bool BIAS, bool RELU, bool SCALE>
__global__ __launch_bounds__(256) void k_gemm(const float* __restrict__ in,
                                              const float* __restrict__ W,
                                              const float* __restrict__ bias,
                                              const float* __restrict__ scale,
                                              float* __restrict__ out, int nrows) {
  int lane = threadIdx.x & 63;
  int wave = threadIdx.x >> 6;
  float w[K];
#pragma unroll
  for (int k = 0; k < K; ++k) w[k] = W[k * 64 + lane];
  float b = BIAS ? bias[lane] : 0.0f;
  int wid = blockIdx.x * 4 + wave;
  int nw = gridDim.x * 4;
  if (wid >= nrows) return;
  float v0 = in[(size_t)wid * K + lane];
  float v1 = 0.f;
  if constexpr (K == 128) v1 = in[(size_t)wid * K + 64 + lane];
  for (int row = wid; row < nrows; row += nw) {
    int nrow = row + nw;
    float nv0 = 0.f, nv1 = 0.f;
    if (nrow < nrows) {
      nv0 = in[(size_t)nrow * K + lane];
      if constexpr (K == 128) nv1 = in[(size_t)nrow * K + 64 + lane];
    }
    float acc0 = b, acc1 = 0.f;
#pragma unroll
    for (int k = 0; k < 64; k += 2) {
      acc0 = fmaf(bcastf(v0, k), w[k], acc0);
      acc1 = fmaf(bcastf(v0, k + 1), w[k + 1], acc1);
    }
    if constexpr (K == 128) {
#pragma unroll
      for (int k = 0; k < 64; k += 2) {
        acc0 = fmaf(bcastf(v1, k), w[64 + k], acc0);
        acc1 = fmaf(bcastf(v1, k + 1), w[64 + k + 1], acc1);
      }
    }
    float r = acc0 + acc1;
    if (RELU) r = fmaxf(r, 0.0f);
    if (SCALE) r *= scale[row];
    out[(size_t)row * 64 + lane] = r;
    v0 = nv0;
    v1 = nv1;
  }
}

// ---------------------------------------------------------------------------
// CSR build: LDS-binned counting sort.
// ---------------------------------------------------------------------------
__global__ __launch_bounds__(256) void k_ccount(const int* __restrict__ dst,
                                                const int* __restrict__ he,
                                                const int* __restrict__ hv,
                                                int* __restrict__ gcnt) {
  __shared__ int hist[NBUK];
  for (int b = threadIdx.x; b < NBUK; b += 256) hist[b] = 0;
  __syncthreads();
  int step = gridDim.x * 256;
  for (int j = blockIdx.x * 256 + threadIdx.x; j < TOT; j += step) {
    int id;
    if (j < NE) id = dst[j];
    else if (j < NE + NZ) id = NN + he[j - NE];
    else id = NN + NH + hv[j - NE - NZ];
    atomicAdd(&hist[id >> 8], 1);
  }
  __syncthreads();
  for (int b = threadIdx.x; b < NBUK; b += 256) {
    int c = hist[b];
    if (c) atomicAdd(&gcnt[b], c);
  }
}

__global__ __launch_bounds__(1024) void k_cscan(const int* __restrict__ gcnt,
                                                int* __restrict__ gbase,
                                                int* __restrict__ gcur) {
  __shared__ int sh[1024];
  int t = threadIdx.x;
  int v = (t < NBUK) ? gcnt[t] : 0;
  sh[t] = v;
  __syncthreads();
#pragma unroll
  for (int d = 1; d < 1024; d <<= 1) {
    int x = (t >= d) ? sh[t - d] : 0;
    __syncthreads();
    sh[t] += x;
    __syncthreads();
  }
  int excl = sh[t] - v;
  if (t < NBUK) {
    gbase[t] = excl;
    gcur[t] = excl;
  }
  if (t == 1023) gbase[NBUK] = sh[1023];
}

__global__ __launch_bounds__(1024) void k_phase1(const int* __restrict__ src,
                                                 const int* __restrict__ dst,
                                                 const int* __restrict__ he,
                                                 const int* __restrict__ hv,
                                                 int* __restrict__ gcur,
                                                 int* __restrict__ adj) {
  __shared__ int cnt[NBUK], base[NBUK], cur[NBUK];
  int tid = threadIdx.x;
  for (int b = tid; b < NBUK; b += 1024) { cnt[b] = 0; cur[b] = 0; }
  __syncthreads();
  int per = (TOT + NWG1 - 1) / NWG1;
  int s0 = blockIdx.x * per;
  int s1 = s0 + per; if (s1 > TOT) s1 = TOT;
  for (int j = s0 + tid; j < s1; j += 1024) {
    int id;
    if (j < NE) id = dst[j];
    else if (j < NE + NZ) id = NN + he[j - NE];
    else id = NN + NH + hv[j - NE - NZ];
    atomicAdd(&cnt[id >> 8], 1);
  }
  __syncthreads();
  for (int b = tid; b < NBUK; b += 1024) {
    int c = cnt[b];
    if (c) base[b] = atomicAdd(&gcur[b], c);
  }
  __syncthreads();
  for (int j = s0 + tid; j < s1; j += 1024) {
    int id, val;
    if (j < NE)           { id = dst[j];                val = src[j]; }
    else if (j < NE + NZ) { id = NN + he[j - NE];       val = hv[j - NE]; }
    else                  { id = NN + NH + hv[j - NE - NZ]; val = he[j - NE - NZ]; }
    int b = id >> 8;
    int slot = base[b] + atomicAdd(&cur[b], 1);
    adj[slot] = ((id & 255) << 17) | val;   // val < 131072
  }
}

__global__ __launch_bounds__(256) void k_phase2(const int* __restrict__ gbase,
                                                int* __restrict__ adj,
                                                int* __restrict__ off) {
  __shared__ int ent[P2CAP];
  __shared__ int hist[256];
  int b = blockIdx.x, tid = threadIdx.x;
  int s = gbase[b];
  int n = gbase[b + 1] - s;
  if (n > P2CAP) n = P2CAP;  // safety; cannot trigger on this dataset
  hist[tid] = 0;
  __syncthreads();
  for (int k = tid; k < n; k += 256) {
    int v = adj[s + k];
    ent[k] = v;
    atomicAdd(&hist[v >> 17], 1);
  }
  __syncthreads();
  int c = hist[tid];
#pragma unroll
  for (int d = 1; d < 256; d <<= 1) {
    int x = (tid >= d) ? hist[tid - d] : 0;
    __syncthreads();
    hist[tid] += x;
    __syncthreads();
  }
  int excl = hist[tid] - c;
  hist[tid] = excl;
  int gid = (b << 8) + tid;
  if (gid <= NS) off[gid] = s + excl;
  __syncthreads();
  for (int k = tid; k < n; k += 256) {
    int v = ent[k];
    int pos = atomicAdd(&hist[v >> 17], 1);
    adj[s + pos] = v & 0x1FFFF;   // store bare value
  }
}

__global__ void k_dinv(const int* __restrict__ off, float* __restrict__ dinv) {
  int i = blockIdx.x * 256 + threadIdx.x;
  if (i < NN) dinv[i] = rsqrtf((float)(off[i + 1] - off[i] + 1));  // +1 self-loop
}

// ---------------------------------------------------------------------------
// Batched row-gather accumulate: 8 independent 256B loads in flight.
// [R6-proven: VGPR ~64, compiler keeps all 8 outstanding]
// Uses `beg`, `end`, `adj`, `lane` from enclosing scope.
// ---------------------------------------------------------------------------
#define GATHER_ROWS8(ROWS, ACCUM_STMT)                                  \
  for (int j0 = beg; j0 < end; j0 += 64) {                              \
    int m = end - j0; if (m > 64) m = 64;                               \
    int a = (lane < m) ? adj[j0 + lane] : 0;                            \
    int k = 0;                                                          \
    for (; k + 8 <= m; k += 8) {                                        \
      int s0 = __shfl(a, k),     s1 = __shfl(a, k + 1);                 \
      int s2 = __shfl(a, k + 2), s3 = __shfl(a, k + 3);                 \
      int s4 = __shfl(a, k + 4), s5 = __shfl(a, k + 5);                 \
      int s6 = __shfl(a, k + 6), s7 = __shfl(a, k + 7);                 \
      float r0 = ROWS[(size_t)s0 * 64 + lane];                          \
      float r1 = ROWS[(size_t)s1 * 64 + lane];                          \
      float r2 = ROWS[(size_t)s2 * 64 + lane];                          \
      float r3 = ROWS[(size_t)s3 * 64 + lane];                          \
      float r4 = ROWS[(size_t)s4 * 64 + lane];                          \
      float r5 = ROWS[(size_t)s5 * 64 + lane];                          \
      float r6 = ROWS[(size_t)s6 * 64 + lane];                          \
      float r7 = ROWS[(size_t)s7 * 64 + lane];                          \
      ACCUM_STMT(r0); ACCUM_STMT(r1); ACCUM_STMT(r2); ACCUM_STMT(r3);   \
      ACCUM_STMT(r4); ACCUM_STMT(r5); ACCUM_STMT(r6); ACCUM_STMT(r7);   \
    }                                                                   \
    for (; k < m; ++k) {                                                \
      float r0 = ROWS[(size_t)__shfl(a, k) * 64 + lane];                \
      ACCUM_STMT(r0);                                                   \
    }                                                                   \
  }

// ---------------------------------------------------------------------------
// conv1 gather (xw1p pre-scaled by dinv[row]):
//   t'[i] = dinv[i] * ( relu( dinv[i]*(sum_s xw1p[s] + xw1p[i]) + conv1_b ) . u )
// ---------------------------------------------------------------------------
__global__ __launch_bounds__(256) void k_gcn1_gather(const int* __restrict__ off,
                                                     const int* __restrict__ adj,
                                                     const float* __restrict__ xw1p,
                                                     const float* __restrict__ dinv,
                                                     const float* __restrict__ conv1_b,
                                                     const float* __restrict__ sv,
                                                     float* __restrict__ tp) {
  int i = blockIdx.x * 4 + (threadIdx.x >> 6);
  if (i >= NN) return;
  int lane = threadIdx.x & 63;
  int beg = off[i], end = off[i + 1];
  float acc = 0.f;
#define ACC_ADD(r) acc += (r)
  GATHER_ROWS8(xw1p, ACC_ADD)
#undef ACC_ADD
  float di = dinv[i];
  float r = fmaxf(fmaf(acc + xw1p[(size_t)i * 64 + lane], di, conv1_b[lane]), 0.f);
  float p = waveReduceSum(r * sv[lane]);
  if (lane == 0) tp[i] = p * di;
}

// ---------------------------------------------------------------------------
// Xe gather + batched matvec. One wave handles 16 hyperedges:  [R6-proven]
// phase A: mean rows -> per-wave LDS (8-deep gather);
// phase B: B[e,:] = m @ W2[64:,:] + b2, W2 streamed from L1.
// ---------------------------------------------------------------------------
__global__ __launch_bounds__(256) void k_xe_gather(const int* __restrict__ off,
                                                   const int* __restrict__ adj,
                                                   const float* __restrict__ C,
                                                   const float* __restrict__ W2,
                                                   const float* __restrict__ b2,
                                                   float* __restrict__ B) {
  __shared__ float hp[4][16][64];
  int lane = threadIdx.x & 63, wv = threadIdx.x >> 6;
  int base = (blockIdx.x * 4 + wv) * 16;
  if (base >= NH) return;
  int ncnt = NH - base; if (ncnt > 16) ncnt = 16;
  for (int n = 0; n < ncnt; ++n) {
    int e = base + n;
    int beg = off[NN + e], end = off[NN + e + 1];
    float acc = 0.f;
#define ACC_ADD(r) acc += (r)
    GATHER_ROWS8(C, ACC_ADD)
#undef ACC_ADD
    hp[wv][n][lane] = acc / fmaxf((float)(end - beg), 1.0f);
  }
  float bb = b2[lane];
  float acc[16];
#pragma unroll
  for (int n = 0; n < 16; ++n) acc[n] = bb;
  for (int k = 0; k < 64; ++k) {
    float wk = W2[(64 + k) * 64 + lane];
#pragma unroll
    for (int n = 0; n < 16; ++n) acc[n] = fmaf(hp[wv][n][k], wk, acc[n]);
  }
#pragma unroll
  for (int n = 0; n < 16; ++n)
    if (n < ncnt) B[(size_t)(base + n) * 64 + lane] = acc[n];
}

// ---------------------------------------------------------------------------
// Final fused kernel. One wave handles 16 nodes:  [R6-proven: 148 us]
// phase A (per node): xv-gather over hv-CSR (8-deep) -> hpre row into LDS;
//                     gcn2 scalar gather -> per-node scalar into LDS.
// phase B: batched hfin = relu(hpre@Wu+bu); out = hfin.w2v + scalar.
// ---------------------------------------------------------------------------
__global__ __launch_bounds__(256) void k_final(const int* __restrict__ off,
                                               const int* __restrict__ adj,
                                               const float* __restrict__ A,
                                               const float* __restrict__ B,
                                               const float* __restrict__ h,
                                               const float* __restrict__ tp,
                                               const float* __restrict__ dinv,
                                               const float* __restrict__ Wu,
                                               const float* __restrict__ bu,
                                               const float* __restrict__ sv,
                                               float* __restrict__ out) {
  __shared__ float hp[4][16][64];
  __shared__ float sarr[4][16];
  int lane = threadIdx.x & 63, wv = threadIdx.x >> 6;
  int base = (blockIdx.x * 4 + wv) * 16;
  if (base >= NN) return;
  int ncnt = NN - base; if (ncnt > 16) ncnt = 16;
  float c_all = sv[128];
  for (int n = 0; n < ncnt; ++n) {
    int i = base + n;
    float av = A[(size_t)i * 64 + lane];
    int beg = off[NN + NH + i], end = off[NN + NH + i + 1];
    float accm = 0.f;
#define ACC_RELU(r) accm += fmaxf(av + (r), 0.f)
    GATHER_ROWS8(B, ACC_RELU)
#undef ACC_RELU
    hp[wv][n][lane] = accm * (0.5f / fmaxf((float)(end - beg), 1.0f)) +
                      0.5f * h[(size_t)i * 64 + lane];
    // gcn2 scalar gather over dst-CSR
    float di = dinv[i];
    int db = off[i], de = off[i + 1];
    float g = 0.f;
    for (int j = db + lane; j < de; j += 64) g += tp[adj[j]];
    float gr = waveReduceSum(g);
    if (lane == 0) sarr[wv][n] = gr * di + tp[i] * di + c_all;
  }
  float bb = bu[lane];
  float w2v = sv[64 + lane];
  float acc[16];
#pragma unroll
  for (int n = 0; n < 16; ++n) acc[n] = bb;
  for (int k = 0; k < 64; ++k) {
    float wk = Wu[k * 64 + lane];
#pragma unroll
    for (int n = 0; n < 16; ++n) acc[n] = fmaf(hp[wv][n][k], wk, acc[n]);
  }
#pragma unroll
  for (int n = 0; n < 16; ++n) {
    if (n < ncnt) {
      float part = fmaxf(acc[n], 0.f) * w2v;
      float tot = waveReduceSum(part);
      if (lane == 0) out[base + n] = tot + sarr[wv][n];
    }
  }
}

// ---------------------------------------------------------------------------
extern "C" void kernel_launch(void* const* d_in, const int* in_sizes, int n_in,
                              void* d_out, int out_size, void* d_ws, size_t ws_size,
                              hipStream_t stream) {
  (void)in_sizes; (void)n_in; (void)out_size; (void)ws_size;
  const float* x       = (const float*)d_in[0];
  const int*   ei      = (const int*)d_in[1];
  const int*   hv      = (const int*)d_in[2];
  const int*   he      = (const int*)d_in[3];
  const float* conv1_W = (const float*)d_in[5];
  const float* conv1_b = (const float*)d_in[6];
  const float* conv2_W = (const float*)d_in[7];
  const float* conv2_b = (const float*)d_in[8];
  const float* lin_W   = (const float*)d_in[9];
  const float* lin_b   = (const float*)d_in[10];
  const float* W1      = (const float*)d_in[11];
  const float* b1      = (const float*)d_in[12];
  const float* W2      = (const float*)d_in[13];
  const float* b2      = (const float*)d_in[14];
  const float* Wu      = (const float*)d_in[15];
  const float* bu      = (const float*)d_in[16];
  const float* cls_W   = (const float*)d_in[17];
  const float* cls_b   = (const float*)d_in[18];
  const float* lp_W    = (const float*)d_in[19];
  const float* lp_b    = (const float*)d_in[20];
  const float* head_W  = (const float*)d_in[21];
  const float* head_b  = (const float*)d_in[22];
  const int* src = ei;
  const int* dst = ei + NE;
  float* out = (float*)d_out;

  // workspace (4B units). Aliasing: P = xw1' -> C.
  float* H     = (float*)d_ws;             // N*64
  float* P     = H + (size_t)NN * 64;      // N*64   xw1' then C
  float* Q     = P + (size_t)NN * 64;      // N*64   A
  float* XE    = Q + (size_t)NN * 64;      // NH*64  B
  float* DINV  = XE + (size_t)NH * 64;     // N
  float* TP    = DINV + NN;                // N   t' = t*dinv
  float* SV    = TP + NN;                  // 192
  int* GCNT    = (int*)(SV + 192);         // NBUK
  int* GBASE   = GCNT + NBUK;              // NBUK+1
  int* GCUR    = GBASE + NBUK + 1;         // NBUK
  int* OFF     = GCUR + NBUK;              // NS+1
  int* ADJ     = OFF + NS + 1;             // TOT
  // total ~95 MiB

  hipMemsetAsync(GCNT, 0, NBUK * 4, stream);

  k_vecs<<<1, 64, 0, stream>>>(conv2_W, conv2_b, cls_W, cls_b, lp_W, lp_b, head_W, head_b, SV);

  // CSR build (LDS-binned counting sort)
  k_ccount<<<512, 256, 0, stream>>>(dst, he, hv, GCNT);
  k_cscan<<<1, 1024, 0, stream>>>(GCNT, GBASE, GCUR);
  k_phase1<<<NWG1, 1024, 0, stream>>>(src, dst, he, hv, GCUR, ADJ);
  k_phase2<<<NBUK, 256, 0, stream>>>(GBASE, ADJ, OFF);
  k_dinv<<<(NN + 255) / 256, 256, 0, stream>>>(OFF, DINV);

  // dense: xw1' = (x @ conv1_W) * dinv[row]; h = relu(x @ lin_W + lin_b)
  k_gemm<128, false, false, true><<<2048, 256, 0, stream>>>(x, conv1_W, nullptr, DINV, P, NN);
  k_gemm<128, true, true, false><<<2048, 256, 0, stream>>>(x, lin_W, lin_b, nullptr, H, NN);

  // GCN branch collapsed to t' (conv2 folded into k_final)
  k_gcn1_gather<<<NN / 4, 256, 0, stream>>>(OFF, ADJ, P, DINV, conv1_b, SV, TP);

  // hyper branch dense parts: A = h @ W2[:64] (Q), C = h @ W1 + b1 (P)
  k_gemm<64, false, false, false><<<2048, 256, 0, stream>>>(H, W2, nullptr, nullptr, Q, NN);
  k_gemm<64, true, false, false><<<2048, 256, 0, stream>>>(H, W1, b1, nullptr, P, NN);

  // 16 hyperedges per wave -> 3125 waves -> 782 blocks
  k_xe_gather<<<782, 256, 0, stream>>>(OFF, ADJ, P, W2, b2, XE);

  // 16 nodes per wave -> 6250 waves -> 1563 blocks
  k_final<<<1563, 256, 0, stream>>>(OFF, ADJ, Q, XE, H, TP, DINV, Wu, bu, SV, out);
}

// Round 10
// 469.307 us; speedup vs baseline: 1.2284x; 1.0591x over previous
//
#include <hip/hip_runtime.h>

#define NN 100000   // nodes
#define NF 128      // input features
#define D  64       // hidden dim
#define NE 1600000  // edges
#define NZ 1000000  // hypergraph incidences
#define NH 50000    // hyperedges

#define NS (NN + NH + NN)          // 250000 concatenated id space
#define TOT (NE + 2 * NZ)          // 3600000 adjacency entries
#define NBUK 977                   // ceil(NS/256) buckets of 256 ids
#define NWG1 256                   // phase-1 workgroups
#define P2CAP 6144                 // max entries per bucket

static __device__ __forceinline__ float waveReduceSum(float v) {
#pragma unroll
  for (int off = 32; off > 0; off >>= 1) v += __shfl_down(v, off);
  return v;
}

// Wave-uniform broadcast via readlane (VALU pipe) — used in GEMMs only.
static __device__ __forceinline__ float bcastf(float v, int l) {
  return __int_as_float(__builtin_amdgcn_readlane(__float_as_int(v), l));
}

// ---------------------------------------------------------------------------
// sv[0:64)   u    = conv2_W @ v1          (v1 = lp_W[:64] @ head_W)
// sv[64:128) w2v  = cls_W  @ v2           (v2 = lp_W[64:] @ head_W)
// sv[128]    c_all= lp_b.head_W + head_b + conv2_b.v1 + cls_b.v2
// ---------------------------------------------------------------------------
__global__ void k_vecs(const float* __restrict__ conv2_W, const float* __restrict__ conv2_b,
                       const float* __restrict__ cls_W, const float* __restrict__ cls_b,
                       const float* __restrict__ lp_W, const float* __restrict__ lp_b,
                       const float* __restrict__ head_W, const float* __restrict__ head_b,
                       float* __restrict__ sv) {
  int t = threadIdx.x;  // 0..63, one wave
  __shared__ float v1[64], v2[64];
  float a1 = 0.f, a2 = 0.f;
  for (int c = 0; c < 64; ++c) {
    float hw = head_W[c];
    a1 = fmaf(lp_W[t * 64 + c], hw, a1);
    a2 = fmaf(lp_W[(64 + t) * 64 + c], hw, a2);
  }
  v1[t] = a1;
  v2[t] = a2;
  __syncthreads();
  float u = 0.f, w = 0.f;
  for (int c = 0; c < 64; ++c) {
    u = fmaf(conv2_W[t * 64 + c], v1[c], u);
    w = fmaf(cls_W[t * 64 + c], v2[c], w);
  }
  sv[t] = u;
  sv[64 + t] = w;
  float part = lp_b[t] * head_W[t] + conv2_b[t] * v1[t] + cls_b[t] * v2[t];
  part = waveReduceSum(part);
  if (t == 0) sv[128] = part + head_b[0];
}

// ---------------------------------------------------------------------------
// Tall-skinny GEMM: out[r,c] = scale?*(act(in[r,:K] @ W[K,64] + b[c]))
// readlane broadcast (VALU) + next-row prefetch.  [R7-proven]
// ---------------------------------------------------------------------------
template <int K, bool BIAS, bool RELU, bool SCALE>
__global__ __launch_bounds__(256) void k_gemm(const float* __restrict__ in,
                                              const float* __restrict__ W,
                                              const float* __restrict__ bias,
                                              const float* __restrict__ scale,
                                              float* __restrict__ out, int nrows) {
  int lane = threadIdx.x & 63;
  int wave = threadIdx.x >> 6;
  float w[K];
#pragma unroll
  for (int k = 0; k < K; ++k) w[k] = W[k * 64 + lane];
  float b = BIAS ? bias[lane] : 0.0f;
  int wid = blockIdx.x * 4 + wave;
  int nw = gridDim.x * 4;
  if (wid >= nrows) return;
  float v0 = in[(size_t)wid * K + lane];
  float v1 = 0.f;
  if constexpr (K == 128) v1 = in[(size_t)wid * K + 64 + lane];
  for (int row = wid; row < nrows; row += nw) {
    int nrow = row + nw;
    float nv0 = 0.f, nv1 = 0.f;
    if (nrow < nrows) {
      nv0 = in[(size_t)nrow * K + lane];
      if constexpr (K == 128) nv1 = in[(size_t)nrow * K + 64 + lane];
    }
    float acc0 = b, acc1 = 0.f;
#pragma unroll
    for (int k = 0; k < 64; k += 2) {
      acc0 = fmaf(bcastf(v0, k), w[k], acc0);
      acc1 = fmaf(bcastf(v0, k + 1), w[k + 1], acc1);
    }
    if constexpr (K == 128) {
#pragma unroll
      for (int k = 0; k < 64; k += 2) {
        acc0 = fmaf(bcastf(v1, k), w[64 + k], acc0);
        acc1 = fmaf(bcastf(v1, k + 1), w[64 + k + 1], acc1);
      }
    }
    float r = acc0 + acc1;
    if (RELU) r = fmaxf(r, 0.0f);
    if (SCALE) r *= scale[row];
    out[(size_t)row * 64 + lane] = r;
    v0 = nv0;
    v1 = nv1;
  }
}

// ---------------------------------------------------------------------------
// CSR build: LDS-binned counting sort.
// ---------------------------------------------------------------------------
__global__ __launch_bounds__(256) void k_ccount(const int* __restrict__ dst,
                                                const int* __restrict__ he,
                                                const int* __restrict__ hv,
                                                int* __restrict__ gcnt) {
  __shared__ int hist[NBUK];
  for (int b = threadIdx.x; b < NBUK; b += 256) hist[b] = 0;
  __syncthreads();
  int step = gridDim.x * 256;
  for (int j = blockIdx.x * 256 + threadIdx.x; j < TOT; j += step) {
    int id;
    if (j < NE) id = dst[j];
    else if (j < NE + NZ) id = NN + he[j - NE];
    else id = NN + NH + hv[j - NE - NZ];
    atomicAdd(&hist[id >> 8], 1);
  }
  __syncthreads();
  for (int b = threadIdx.x; b < NBUK; b += 256) {
    int c = hist[b];
    if (c) atomicAdd(&gcnt[b], c);
  }
}

__global__ __launch_bounds__(1024) void k_cscan(const int* __restrict__ gcnt,
                                                int* __restrict__ gbase,
                                                int* __restrict__ gcur) {
  __shared__ int sh[1024];
  int t = threadIdx.x;
  int v = (t < NBUK) ? gcnt[t] : 0;
  sh[t] = v;
  __syncthreads();
#pragma unroll
  for (int d = 1; d < 1024; d <<= 1) {
    int x = (t >= d) ? sh[t - d] : 0;
    __syncthreads();
    sh[t] += x;
    __syncthreads();
  }
  int excl = sh[t] - v;
  if (t < NBUK) {
    gbase[t] = excl;
    gcur[t] = excl;
  }
  if (t == 1023) gbase[NBUK] = sh[1023];
}

__global__ __launch_bounds__(1024) void k_phase1(const int* __restrict__ src,
                                                 const int* __restrict__ dst,
                                                 const int* __restrict__ he,
                                                 const int* __restrict__ hv,
                                                 int* __restrict__ gcur,
                                                 int* __restrict__ adj) {
  __shared__ int cnt[NBUK], base[NBUK], cur[NBUK];
  int tid = threadIdx.x;
  for (int b = tid; b < NBUK; b += 1024) { cnt[b] = 0; cur[b] = 0; }
  __syncthreads();
  int per = (TOT + NWG1 - 1) / NWG1;
  int s0 = blockIdx.x * per;
  int s1 = s0 + per; if (s1 > TOT) s1 = TOT;
  for (int j = s0 + tid; j < s1; j += 1024) {
    int id;
    if (j < NE) id = dst[j];
    else if (j < NE + NZ) id = NN + he[j - NE];
    else id = NN + NH + hv[j - NE - NZ];
    atomicAdd(&cnt[id >> 8], 1);
  }
  __syncthreads();
  for (int b = tid; b < NBUK; b += 1024) {
    int c = cnt[b];
    if (c) base[b] = atomicAdd(&gcur[b], c);
  }
  __syncthreads();
  for (int j = s0 + tid; j < s1; j += 1024) {
    int id, val;
    if (j < NE)           { id = dst[j];                val = src[j]; }
    else if (j < NE + NZ) { id = NN + he[j - NE];       val = hv[j - NE]; }
    else                  { id = NN + NH + hv[j - NE - NZ]; val = he[j - NE - NZ]; }
    int b = id >> 8;
    int slot = base[b] + atomicAdd(&cur[b], 1);
    adj[slot] = ((id & 255) << 17) | val;   // val < 131072
  }
}

__global__ __launch_bounds__(256) void k_phase2(const int* __restrict__ gbase,
                                                int* __restrict__ adj,
                                                int* __restrict__ off) {
  __shared__ int ent[P2CAP];
  __shared__ int hist[256];
  int b = blockIdx.x, tid = threadIdx.x;
  int s = gbase[b];
  int n = gbase[b + 1] - s;
  if (n > P2CAP) n = P2CAP;  // safety; cannot trigger on this dataset
  hist[tid] = 0;
  __syncthreads();
  for (int k = tid; k < n; k += 256) {
    int v = adj[s + k];
    ent[k] = v;
    atomicAdd(&hist[v >> 17], 1);
  }
  __syncthreads();
  int c = hist[tid];
#pragma unroll
  for (int d = 1; d < 256; d <<= 1) {
    int x = (tid >= d) ? hist[tid - d] : 0;
    __syncthreads();
    hist[tid] += x;
    __syncthreads();
  }
  int excl = hist[tid] - c;
  hist[tid] = excl;
  int gid = (b << 8) + tid;
  if (gid <= NS) off[gid] = s + excl;
  __syncthreads();
  for (int k = tid; k < n; k += 256) {
    int v = ent[k];
    int pos = atomicAdd(&hist[v >> 17], 1);
    adj[s + pos] = v & 0x1FFFF;   // store bare value
  }
}

__global__ void k_dinv(const int* __restrict__ off, float* __restrict__ dinv) {
  int i = blockIdx.x * 256 + threadIdx.x;
  if (i < NN) dinv[i] = rsqrtf((float)(off[i + 1] - off[i] + 1));  // +1 self-loop
}

// ---------------------------------------------------------------------------
// Predicated batched row-gather: ALWAYS issue 8 loads per batch (index clamped
// to m-1 -> duplicates hit L1), accumulate under uniform predicate k+q<m.
// No serial remainder loop -> every batch costs ~1 latency, not up to 7.
// Uses `beg`, `end`, `adj`, `lane` from enclosing scope.
// ---------------------------------------------------------------------------
#define GATHER_ROWS8(ROWS, ACCUM_STMT)                                  \
  for (int j0 = beg; j0 < end; j0 += 64) {                              \
    int m = end - j0; if (m > 64) m = 64;                               \
    int a = (lane < m) ? adj[j0 + lane] : 0;                            \
    for (int k = 0; k < m; k += 8) {                                    \
      int s_[8]; float r_[8];                                           \
      _Pragma("unroll")                                                 \
      for (int q = 0; q < 8; ++q) {                                     \
        int kk = k + q; kk = (kk < m - 1) ? kk : (m - 1);               \
        s_[q] = __shfl(a, kk);                                          \
      }                                                                 \
      _Pragma("unroll")                                                 \
      for (int q = 0; q < 8; ++q) r_[q] = ROWS[(size_t)s_[q] * 64 + lane]; \
      _Pragma("unroll")                                                 \
      for (int q = 0; q < 8; ++q) {                                     \
        if (k + q < m) { ACCUM_STMT(r_[q]); }                           \
      }                                                                 \
    }                                                                   \
  }

// ---------------------------------------------------------------------------
// conv1 gather (xw1p pre-scaled by dinv[row]):
//   t'[i] = dinv[i] * ( relu( dinv[i]*(sum_s xw1p[s] + xw1p[i]) + conv1_b ) . u )
// ---------------------------------------------------------------------------
__global__ __launch_bounds__(256) void k_gcn1_gather(const int* __restrict__ off,
                                                     const int* __restrict__ adj,
                                                     const float* __restrict__ xw1p,
                                                     const float* __restrict__ dinv,
                                                     const float* __restrict__ conv1_b,
                                                     const float* __restrict__ sv,
                                                     float* __restrict__ tp) {
  int i = blockIdx.x * 4 + (threadIdx.x >> 6);
  if (i >= NN) return;
  int lane = threadIdx.x & 63;
  int beg = off[i], end = off[i + 1];
  float acc = 0.f;
#define ACC_ADD(r) acc += (r)
  GATHER_ROWS8(xw1p, ACC_ADD)
#undef ACC_ADD
  float di = dinv[i];
  float r = fmaxf(fmaf(acc + xw1p[(size_t)i * 64 + lane], di, conv1_b[lane]), 0.f);
  float p = waveReduceSum(r * sv[lane]);
  if (lane == 0) tp[i] = p * di;
}

// ---------------------------------------------------------------------------
// Xe gather + batched matvec. One wave handles 16 hyperedges:
// phase A: mean rows -> per-wave LDS (predicated 8-deep gather);
// phase B: B[e,:] = m @ W2[64:,:] + b2, W2 streamed from L1.
// ---------------------------------------------------------------------------
__global__ __launch_bounds__(256) void k_xe_gather(const int* __restrict__ off,
                                                   const int* __restrict__ adj,
                                                   const float* __restrict__ C,
                                                   const float* __restrict__ W2,
                                                   const float* __restrict__ b2,
                                                   float* __restrict__ B) {
  __shared__ float hp[4][16][64];
  int lane = threadIdx.x & 63, wv = threadIdx.x >> 6;
  int base = (blockIdx.x * 4 + wv) * 16;
  if (base >= NH) return;
  int ncnt = NH - base; if (ncnt > 16) ncnt = 16;
  for (int n = 0; n < ncnt; ++n) {
    int e = base + n;
    int beg = off[NN + e], end = off[NN + e + 1];
    float acc = 0.f;
#define ACC_ADD(r) acc += (r)
    GATHER_ROWS8(C, ACC_ADD)
#undef ACC_ADD
    hp[wv][n][lane] = acc / fmaxf((float)(end - beg), 1.0f);
  }
  float bb = b2[lane];
  float acc[16];
#pragma unroll
  for (int n = 0; n < 16; ++n) acc[n] = bb;
  for (int k = 0; k < 64; ++k) {
    float wk = W2[(64 + k) * 64 + lane];
#pragma unroll
    for (int n = 0; n < 16; ++n) acc[n] = fmaf(hp[wv][n][k], wk, acc[n]);
  }
#pragma unroll
  for (int n = 0; n < 16; ++n)
    if (n < ncnt) B[(size_t)(base + n) * 64 + lane] = acc[n];
}

// ---------------------------------------------------------------------------
// Final fused kernel. One wave handles 16 nodes:
// phase A (per node): xv-gather over hv-CSR (predicated 8-deep) -> hpre in LDS;
//                     gcn2 scalar gather -> per-node scalar into LDS.
// phase B: batched hfin = relu(hpre@Wu+bu); out = hfin.w2v + scalar.
// ---------------------------------------------------------------------------
__global__ __launch_bounds__(256) void k_final(const int* __restrict__ off,
                                               const int* __restrict__ adj,
                                               const float* __restrict__ A,
                                               const float* __restrict__ B,
                                               const float* __restrict__ h,
                                               const float* __restrict__ tp,
                                               const float* __restrict__ dinv,
                                               const float* __restrict__ Wu,
                                               const float* __restrict__ bu,
                                               const float* __restrict__ sv,
                                               float* __restrict__ out) {
  __shared__ float hp[4][16][64];
  __shared__ float sarr[4][16];
  int lane = threadIdx.x & 63, wv = threadIdx.x >> 6;
  int base = (blockIdx.x * 4 + wv) * 16;
  if (base >= NN) return;
  int ncnt = NN - base; if (ncnt > 16) ncnt = 16;
  float c_all = sv[128];
  for (int n = 0; n < ncnt; ++n) {
    int i = base + n;
    float av = A[(size_t)i * 64 + lane];
    int beg = off[NN + NH + i], end = off[NN + NH + i + 1];
    float accm = 0.f;
#define ACC_RELU(r) accm += fmaxf(av + (r), 0.f)
    GATHER_ROWS8(B, ACC_RELU)
#undef ACC_RELU
    hp[wv][n][lane] = accm * (0.5f / fmaxf((float)(end - beg), 1.0f)) +
                      0.5f * h[(size_t)i * 64 + lane];
    // gcn2 scalar gather over dst-CSR
    float di = dinv[i];
    int db = off[i], de = off[i + 1];
    float g = 0.f;
    for (int j = db + lane; j < de; j += 64) g += tp[adj[j]];
    float gr = waveReduceSum(g);
    if (lane == 0) sarr[wv][n] = gr * di + tp[i] * di + c_all;
  }
  float bb = bu[lane];
  float w2v = sv[64 + lane];
  float acc[16];
#pragma unroll
  for (int n = 0; n < 16; ++n) acc[n] = bb;
  for (int k = 0; k < 64; ++k) {
    float wk = Wu[k * 64 + lane];
#pragma unroll
    for (int n = 0; n < 16; ++n) acc[n] = fmaf(hp[wv][n][k], wk, acc[n]);
  }
#pragma unroll
  for (int n = 0; n < 16; ++n) {
    if (n < ncnt) {
      float part = fmaxf(acc[n], 0.f) * w2v;
      float tot = waveReduceSum(part);
      if (lane == 0) out[base + n] = tot + sarr[wv][n];
    }
  }
}

// ---------------------------------------------------------------------------
extern "C" void kernel_launch(void* const* d_in, const int* in_sizes, int n_in,
                              void* d_out, int out_size, void* d_ws, size_t ws_size,
                              hipStream_t stream) {
  (void)in_sizes; (void)n_in; (void)out_size; (void)ws_size;
  const float* x       = (const float*)d_in[0];
  const int*   ei      = (const int*)d_in[1];
  const int*   hv      = (const int*)d_in[2];
  const int*   he      = (const int*)d_in[3];
  const float* conv1_W = (const float*)d_in[5];
  const float* conv1_b = (const float*)d_in[6];
  const float* conv2_W = (const float*)d_in[7];
  const float* conv2_b = (const float*)d_in[8];
  const float* lin_W   = (const float*)d_in[9];
  const float* lin_b   = (const float*)d_in[10];
  const float* W1      = (const float*)d_in[11];
  const float* b1      = (const float*)d_in[12];
  const float* W2      = (const float*)d_in[13];
  const float* b2      = (const float*)d_in[14];
  const float* Wu      = (const float*)d_in[15];
  const float* bu      = (const float*)d_in[16];
  const float* cls_W   = (const float*)d_in[17];
  const float* cls_b   = (const float*)d_in[18];
  const float* lp_W    = (const float*)d_in[19];
  const float* lp_b    = (const float*)d_in[20];
  const float* head_W  = (const float*)d_in[21];
  const float* head_b  = (const float*)d_in[22];
  const int* src = ei;
  const int* dst = ei + NE;
  float* out = (float*)d_out;

  // workspace (4B units). Aliasing: P = xw1' -> C.
  float* H     = (float*)d_ws;             // N*64
  float* P     = H + (size_t)NN * 64;      // N*64   xw1' then C
  float* Q     = P + (size_t)NN * 64;      // N*64   A
  float* XE    = Q + (size_t)NN * 64;      // NH*64  B
  float* DINV  = XE + (size_t)NH * 64;     // N
  float* TP    = DINV + NN;                // N   t' = t*dinv
  float* SV    = TP + NN;                  // 192
  int* GCNT    = (int*)(SV + 192);         // NBUK
  int* GBASE   = GCNT + NBUK;              // NBUK+1
  int* GCUR    = GBASE + NBUK + 1;         // NBUK
  int* OFF     = GCUR + NBUK;              // NS+1
  int* ADJ     = OFF + NS + 1;             // TOT
  // total ~95 MiB

  hipMemsetAsync(GCNT, 0, NBUK * 4, stream);

  k_vecs<<<1, 64, 0, stream>>>(conv2_W, conv2_b, cls_W, cls_b, lp_W, lp_b, head_W, head_b, SV);

  // CSR build (LDS-binned counting sort)
  k_ccount<<<512, 256, 0, stream>>>(dst, he, hv, GCNT);
  k_cscan<<<1, 1024, 0, stream>>>(GCNT, GBASE, GCUR);
  k_phase1<<<NWG1, 1024, 0, stream>>>(src, dst, he, hv, GCUR, ADJ);
  k_phase2<<<NBUK, 256, 0, stream>>>(GBASE, ADJ, OFF);
  k_dinv<<<(NN + 255) / 256, 256, 0, stream>>>(OFF, DINV);

  // dense: xw1' = (x @ conv1_W) * dinv[row]; h = relu(x @ lin_W + lin_b)
  k_gemm<128, false, false, true><<<2048, 256, 0, stream>>>(x, conv1_W, nullptr, DINV, P, NN);
  k_gemm<128, true, true, false><<<2048, 256, 0, stream>>>(x, lin_W, lin_b, nullptr, H, NN);

  // GCN branch collapsed to t' (conv2 folded into k_final)
  k_gcn1_gather<<<NN / 4, 256, 0, stream>>>(OFF, ADJ, P, DINV, conv1_b, SV, TP);

  // hyper branch dense parts: A = h @ W2[:64] (Q), C = h @ W1 + b1 (P)
  k_gemm<64, false, false, false><<<2048, 256, 0, stream>>>(H, W2, nullptr, nullptr, Q, NN);
  k_gemm<64, true, false, false><<<2048, 256, 0, stream>>>(H, W1, b1, nullptr, P, NN);

  // 16 hyperedges per wave -> 3125 waves -> 782 blocks
  k_xe_gather<<<782, 256, 0, stream>>>(OFF, ADJ, P, W2, b2, XE);

  // 16 nodes per wave -> 6250 waves -> 1563 blocks
  k_final<<<1563, 256, 0, stream>>>(OFF, ADJ, Q, XE, H, TP, DINV, Wu, bu, SV, out);
}

// Round 11
// 449.944 us; speedup vs baseline: 1.2813x; 1.0430x over previous
//
#include <hip/hip_runtime.h>

#define NN 100000   // nodes
#define NF 128      // input features
#define D  64       // hidden dim
#define NE 1600000  // edges
#define NZ 1000000  // hypergraph incidences
#define NH 50000    // hyperedges

#define NS (NN + NH + NN)          // 250000 concatenated id space
#define TOT (NE + 2 * NZ)          // 3600000 adjacency entries
#define NBUK 977                   // ceil(NS/256) buckets of 256 ids
#define NWG1 256                   // phase-1 workgroups
#define P2CAP 6144                 // max entries per bucket

static __device__ __forceinline__ float waveReduceSum(float v) {
#pragma unroll
  for (int off = 32; off > 0; off >>= 1) v += __shfl_down(v, off);
  return v;
}

// Wave-uniform broadcast via readlane (VALU pipe, not ds_bpermute/LDS pipe).
// Index may be a runtime wave-uniform value (lands in SGPR).
static __device__ __forceinline__ float bcastf(float v, int l) {
  return __int_as_float(__builtin_amdgcn_readlane(__float_as_int(v), l));
}

// ---------------------------------------------------------------------------
// sv[0:64)   u    = conv2_W @ v1          (v1 = lp_W[:64] @ head_W)
// sv[64:128) w2v  = cls_W  @ v2           (v2 = lp_W[64:] @ head_W)
// sv[128]    c_all= lp_b.head_W + head_b + conv2_b.v1 + cls_b.v2
// ---------------------------------------------------------------------------
__global__ void k_vecs(const float* __restrict__ conv2_W, const float* __restrict__ conv2_b,
                       const float* __restrict__ cls_W, const float* __restrict__ cls_b,
                       const float* __restrict__ lp_W, const float* __restrict__ lp_b,
                       const float* __restrict__ head_W, const float* __restrict__ head_b,
                       float* __restrict__ sv) {
  int t = threadIdx.x;  // 0..63, one wave
  __shared__ float v1[64], v2[64];
  float a1 = 0.f, a2 = 0.f;
  for (int c = 0; c < 64; ++c) {
    float hw = head_W[c];
    a1 = fmaf(lp_W[t * 64 + c], hw, a1);
    a2 = fmaf(lp_W[(64 + t) * 64 + c], hw, a2);
  }
  v1[t] = a1;
  v2[t] = a2;
  __syncthreads();
  float u = 0.f, w = 0.f;
  for (int c = 0; c < 64; ++c) {
    u = fmaf(conv2_W[t * 64 + c], v1[c], u);
    w = fmaf(cls_W[t * 64 + c], v2[c], w);
  }
  sv[t] = u;
  sv[64 + t] = w;
  float part = lp_b[t] * head_W[t] + conv2_b[t] * v1[t] + cls_b[t] * v2[t];
  part = waveReduceSum(part);
  if (t == 0) sv[128] = part + head_b[0];
}

// ---------------------------------------------------------------------------
// Tall-skinny GEMM: out[r,c] = scale?*(act(in[r,:K] @ W[K,64] + b[c]))
// readlane broadcast (VALU) + next-row prefetch.  [R7-proven]
// ---------------------------------------------------------------------------
template <int K, bool BIAS, bool RELU, bool SCALE>
__global__ __launch_bounds__(256) void k_gemm(const float* __restrict__ in,
                                              const float* __restrict__ W,
                                              const float* __restrict__ bias,
                                              const float* __restrict__ scale,
                                              float* __restrict__ out, int nrows) {
  int lane = threadIdx.x & 63;
  int wave = threadIdx.x >> 6;
  float w[K];
#pragma unroll
  for (int k = 0; k < K; ++k) w[k] = W[k * 64 + lane];
  float b = BIAS ? bias[lane] : 0.0f;
  int wid = blockIdx.x * 4 + wave;
  int nw = gridDim.x * 4;
  if (wid >= nrows) return;
  float v0 = in[(size_t)wid * K + lane];
  float v1 = 0.f;
  if constexpr (K == 128) v1 = in[(size_t)wid * K + 64 + lane];
  for (int row = wid; row < nrows; row += nw) {
    int nrow = row + nw;
    float nv0 = 0.f, nv1 = 0.f;
    if (nrow < nrows) {
      nv0 = in[(size_t)nrow * K + lane];
      if constexpr (K == 128) nv1 = in[(size_t)nrow * K + 64 + lane];
    }
    float acc0 = b, acc1 = 0.f;
#pragma unroll
    for (int k = 0; k < 64; k += 2) {
      acc0 = fmaf(bcastf(v0, k), w[k], acc0);
      acc1 = fmaf(bcastf(v0, k + 1), w[k + 1], acc1);
    }
    if constexpr (K == 128) {
#pragma unroll
      for (int k = 0; k < 64; k += 2) {
        acc0 = fmaf(bcastf(v1, k), w[64 + k], acc0);
        acc1 = fmaf(bcastf(v1, k + 1), w[64 + k + 1], acc1);
      }
    }
    float r = acc0 + acc1;
    if (RELU) r = fmaxf(r, 0.0f);
    if (SCALE) r *= scale[row];
    out[(size_t)row * 64 + lane] = r;
    v0 = nv0;
    v1 = nv1;
  }
}

// ---------------------------------------------------------------------------
// CSR build: LDS-binned counting sort.
// ---------------------------------------------------------------------------
__global__ __launch_bounds__(256) void k_ccount(const int* __restrict__ dst,
                                                const int* __restrict__ he,
                                                const int* __restrict__ hv,
                                                int* __restrict__ gcnt) {
  __shared__ int hist[NBUK];
  for (int b = threadIdx.x; b < NBUK; b += 256) hist[b] = 0;
  __syncthreads();
  int step = gridDim.x * 256;
  for (int j = blockIdx.x * 256 + threadIdx.x; j < TOT; j += step) {
    int id;
    if (j < NE) id = dst[j];
    else if (j < NE + NZ) id = NN + he[j - NE];
    else id = NN + NH + hv[j - NE - NZ];
    atomicAdd(&hist[id >> 8], 1);
  }
  __syncthreads();
  for (int b = threadIdx.x; b < NBUK; b += 256) {
    int c = hist[b];
    if (c) atomicAdd(&gcnt[b], c);
  }
}

__global__ __launch_bounds__(1024) void k_cscan(const int* __restrict__ gcnt,
                                                int* __restrict__ gbase,
                                                int* __restrict__ gcur) {
  __shared__ int sh[1024];
  int t = threadIdx.x;
  int v = (t < NBUK) ? gcnt[t] : 0;
  sh[t] = v;
  __syncthreads();
#pragma unroll
  for (int d = 1; d < 1024; d <<= 1) {
    int x = (t >= d) ? sh[t - d] : 0;
    __syncthreads();
    sh[t] += x;
    __syncthreads();
  }
  int excl = sh[t] - v;
  if (t < NBUK) {
    gbase[t] = excl;
    gcur[t] = excl;
  }
  if (t == 1023) gbase[NBUK] = sh[1023];
}

__global__ __launch_bounds__(1024) void k_phase1(const int* __restrict__ src,
                                                 const int* __restrict__ dst,
                                                 const int* __restrict__ he,
                                                 const int* __restrict__ hv,
                                                 int* __restrict__ gcur,
                                                 int* __restrict__ adj) {
  __shared__ int cnt[NBUK], base[NBUK], cur[NBUK];
  int tid = threadIdx.x;
  for (int b = tid; b < NBUK; b += 1024) { cnt[b] = 0; cur[b] = 0; }
  __syncthreads();
  int per = (TOT + NWG1 - 1) / NWG1;
  int s0 = blockIdx.x * per;
  int s1 = s0 + per; if (s1 > TOT) s1 = TOT;
  for (int j = s0 + tid; j < s1; j += 1024) {
    int id;
    if (j < NE) id = dst[j];
    else if (j < NE + NZ) id = NN + he[j - NE];
    else id = NN + NH + hv[j - NE - NZ];
    atomicAdd(&cnt[id >> 8], 1);
  }
  __syncthreads();
  for (int b = tid; b < NBUK; b += 1024) {
    int c = cnt[b];
    if (c) base[b] = atomicAdd(&gcur[b], c);
  }
  __syncthreads();
  for (int j = s0 + tid; j < s1; j += 1024) {
    int id, val;
    if (j < NE)           { id = dst[j];                val = src[j]; }
    else if (j < NE + NZ) { id = NN + he[j - NE];       val = hv[j - NE]; }
    else                  { id = NN + NH + hv[j - NE - NZ]; val = he[j - NE - NZ]; }
    int b = id >> 8;
    int slot = base[b] + atomicAdd(&cur[b], 1);
    adj[slot] = ((id & 255) << 17) | val;   // val < 131072
  }
}

__global__ __launch_bounds__(256) void k_phase2(const int* __restrict__ gbase,
                                                int* __restrict__ adj,
                                                int* __restrict__ off) {
  __shared__ int ent[P2CAP];
  __shared__ int hist[256];
  int b = blockIdx.x, tid = threadIdx.x;
  int s = gbase[b];
  int n = gbase[b + 1] - s;
  if (n > P2CAP) n = P2CAP;  // safety; cannot trigger on this dataset
  hist[tid] = 0;
  __syncthreads();
  for (int k = tid; k < n; k += 256) {
    int v = adj[s + k];
    ent[k] = v;
    atomicAdd(&hist[v >> 17], 1);
  }
  __syncthreads();
  int c = hist[tid];
#pragma unroll
  for (int d = 1; d < 256; d <<= 1) {
    int x = (tid >= d) ? hist[tid - d] : 0;
    __syncthreads();
    hist[tid] += x;
    __syncthreads();
  }
  int excl = hist[tid] - c;
  hist[tid] = excl;
  int gid = (b << 8) + tid;
  if (gid <= NS) off[gid] = s + excl;
  __syncthreads();
  for (int k = tid; k < n; k += 256) {
    int v = ent[k];
    int pos = atomicAdd(&hist[v >> 17], 1);
    adj[s + pos] = v & 0x1FFFF;   // store bare value
  }
}

__global__ void k_dinv(const int* __restrict__ off, float* __restrict__ dinv) {
  int i = blockIdx.x * 256 + threadIdx.x;
  if (i < NN) dinv[i] = rsqrtf((float)(off[i + 1] - off[i] + 1));  // +1 self-loop
}

// ---------------------------------------------------------------------------
// Predicated batched row-gather: ALWAYS issue 8 loads per batch (index clamped
// to m-1 -> duplicates hit L1), accumulate under uniform predicate k+q<m.
// Uses `beg`, `end`, `adj`, `lane` from enclosing scope.  [R10-proven]
// ---------------------------------------------------------------------------
#define GATHER_ROWS8(ROWS, ACCUM_STMT)                                  \
  for (int j0 = beg; j0 < end; j0 += 64) {                              \
    int m = end - j0; if (m > 64) m = 64;                               \
    int a = (lane < m) ? adj[j0 + lane] : 0;                            \
    for (int k = 0; k < m; k += 8) {                                    \
      int s_[8]; float r_[8];                                           \
      _Pragma("unroll")                                                 \
      for (int q = 0; q < 8; ++q) {                                     \
        int kk = k + q; kk = (kk < m - 1) ? kk : (m - 1);               \
        s_[q] = __shfl(a, kk);                                          \
      }                                                                 \
      _Pragma("unroll")                                                 \
      for (int q = 0; q < 8; ++q) r_[q] = ROWS[(size_t)s_[q] * 64 + lane]; \
      _Pragma("unroll")                                                 \
      for (int q = 0; q < 8; ++q) {                                     \
        if (k + q < m) { ACCUM_STMT(r_[q]); }                           \
      }                                                                 \
    }                                                                   \
  }

// ---------------------------------------------------------------------------
// conv1 gather (xw1p pre-scaled by dinv[row]):
//   t'[i] = dinv[i] * ( relu( dinv[i]*(sum_s xw1p[s] + xw1p[i]) + conv1_b ) . u )
// ---------------------------------------------------------------------------
__global__ __launch_bounds__(256) void k_gcn1_gather(const int* __restrict__ off,
                                                     const int* __restrict__ adj,
                                                     const float* __restrict__ xw1p,
                                                     const float* __restrict__ dinv,
                                                     const float* __restrict__ conv1_b,
                                                     const float* __restrict__ sv,
                                                     float* __restrict__ tp) {
  int i = blockIdx.x * 4 + (threadIdx.x >> 6);
  if (i >= NN) return;
  int lane = threadIdx.x & 63;
  int beg = off[i], end = off[i + 1];
  float acc = 0.f;
#define ACC_ADD(r) acc += (r)
  GATHER_ROWS8(xw1p, ACC_ADD)
#undef ACC_ADD
  float di = dinv[i];
  float r = fmaxf(fmaf(acc + xw1p[(size_t)i * 64 + lane], di, conv1_b[lane]), 0.f);
  float p = waveReduceSum(r * sv[lane]);
  if (lane == 0) tp[i] = p * di;
}

// ---------------------------------------------------------------------------
// Xe gather + batched matvec. One wave handles 16 hyperedges.
// phase A: mean rows -> per-wave LDS (predicated 8-deep gather).
// phase B: matvec via VGPR column re-read (16 vector ds_reads) + readlane
//          broadcast on the VALU pipe (no 1024 scalar LDS reads).
// ---------------------------------------------------------------------------
__global__ __launch_bounds__(256) void k_xe_gather(const int* __restrict__ off,
                                                   const int* __restrict__ adj,
                                                   const float* __restrict__ C,
                                                   const float* __restrict__ W2,
                                                   const float* __restrict__ b2,
                                                   float* __restrict__ B) {
  __shared__ float hp[4][16][64];
  int lane = threadIdx.x & 63, wv = threadIdx.x >> 6;
  int base = (blockIdx.x * 4 + wv) * 16;
  if (base >= NH) return;
  int ncnt = NH - base; if (ncnt > 16) ncnt = 16;
  for (int n = 0; n < ncnt; ++n) {
    int e = base + n;
    int beg = off[NN + e], end = off[NN + e + 1];
    float acc = 0.f;
#define ACC_ADD(r) acc += (r)
    GATHER_ROWS8(C, ACC_ADD)
#undef ACC_ADD
    hp[wv][n][lane] = acc / fmaxf((float)(end - beg), 1.0f);
  }
  // phase B: each lane re-reads its own column (static index -> registers)
  float hv_[16];
#pragma unroll
  for (int n = 0; n < 16; ++n) hv_[n] = hp[wv][n][lane];
  float bb = b2[lane];
  float acc[16];
#pragma unroll
  for (int n = 0; n < 16; ++n) acc[n] = bb;
  for (int k = 0; k < 64; ++k) {
    float wk = W2[(64 + k) * 64 + lane];
#pragma unroll
    for (int n = 0; n < 16; ++n) acc[n] = fmaf(bcastf(hv_[n], k), wk, acc[n]);
  }
#pragma unroll
  for (int n = 0; n < 16; ++n)
    if (n < ncnt) B[(size_t)(base + n) * 64 + lane] = acc[n];
}

// ---------------------------------------------------------------------------
// Final fused kernel. One wave handles 16 nodes.
// phase A (per node): xv-gather over hv-CSR (predicated 8-deep) -> hpre in LDS;
//                     gcn2 scalar gather -> per-node scalar into LDS.
// phase B: matvec via VGPR column re-read + readlane broadcast (VALU pipe);
//          out = relu(hfin).w2v + scalar.
// ---------------------------------------------------------------------------
__global__ __launch_bounds__(256) void k_final(const int* __restrict__ off,
                                               const int* __restrict__ adj,
                                               const float* __restrict__ A,
                                               const float* __restrict__ B,
                                               const float* __restrict__ h,
                                               const float* __restrict__ tp,
                                               const float* __restrict__ dinv,
                                               const float* __restrict__ Wu,
                                               const float* __restrict__ bu,
                                               const float* __restrict__ sv,
                                               float* __restrict__ out) {
  __shared__ float hp[4][16][64];
  __shared__ float sarr[4][16];
  int lane = threadIdx.x & 63, wv = threadIdx.x >> 6;
  int base = (blockIdx.x * 4 + wv) * 16;
  if (base >= NN) return;
  int ncnt = NN - base; if (ncnt > 16) ncnt = 16;
  float c_all = sv[128];
  for (int n = 0; n < ncnt; ++n) {
    int i = base + n;
    float av = A[(size_t)i * 64 + lane];
    int beg = off[NN + NH + i], end = off[NN + NH + i + 1];
    float accm = 0.f;
#define ACC_RELU(r) accm += fmaxf(av + (r), 0.f)
    GATHER_ROWS8(B, ACC_RELU)
#undef ACC_RELU
    hp[wv][n][lane] = accm * (0.5f / fmaxf((float)(end - beg), 1.0f)) +
                      0.5f * h[(size_t)i * 64 + lane];
    // gcn2 scalar gather over dst-CSR
    float di = dinv[i];
    int db = off[i], de = off[i + 1];
    float g = 0.f;
    for (int j = db + lane; j < de; j += 64) g += tp[adj[j]];
    float gr = waveReduceSum(g);
    if (lane == 0) sarr[wv][n] = gr * di + tp[i] * di + c_all;
  }
  // phase B: column re-read to registers, readlane matvec on VALU pipe
  float hv_[16];
#pragma unroll
  for (int n = 0; n < 16; ++n) hv_[n] = hp[wv][n][lane];
  float bb = bu[lane];
  float w2v = sv[64 + lane];
  float acc[16];
#pragma unroll
  for (int n = 0; n < 16; ++n) acc[n] = bb;
  for (int k = 0; k < 64; ++k) {
    float wk = Wu[k * 64 + lane];
#pragma unroll
    for (int n = 0; n < 16; ++n) acc[n] = fmaf(bcastf(hv_[n], k), wk, acc[n]);
  }
#pragma unroll
  for (int n = 0; n < 16; ++n) {
    if (n < ncnt) {
      float part = fmaxf(acc[n], 0.f) * w2v;
      float tot = waveReduceSum(part);
      if (lane == 0) out[base + n] = tot + sarr[wv][n];
    }
  }
}

// ---------------------------------------------------------------------------
extern "C" void kernel_launch(void* const* d_in, const int* in_sizes, int n_in,
                              void* d_out, int out_size, void* d_ws, size_t ws_size,
                              hipStream_t stream) {
  (void)in_sizes; (void)n_in; (void)out_size; (void)ws_size;
  const float* x       = (const float*)d_in[0];
  const int*   ei      = (const int*)d_in[1];
  const int*   hv      = (const int*)d_in[2];
  const int*   he      = (const int*)d_in[3];
  const float* conv1_W = (const float*)d_in[5];
  const float* conv1_b = (const float*)d_in[6];
  const float* conv2_W = (const float*)d_in[7];
  const float* conv2_b = (const float*)d_in[8];
  const float* lin_W   = (const float*)d_in[9];
  const float* lin_b   = (const float*)d_in[10];
  const float* W1      = (const float*)d_in[11];
  const float* b1      = (const float*)d_in[12];
  const float* W2      = (const float*)d_in[13];
  const float* b2      = (const float*)d_in[14];
  const float* Wu      = (const float*)d_in[15];
  const float* bu      = (const float*)d_in[16];
  const float* cls_W   = (const float*)d_in[17];
  const float* cls_b   = (const float*)d_in[18];
  const float* lp_W    = (const float*)d_in[19];
  const float* lp_b    = (const float*)d_in[20];
  const float* head_W  = (const float*)d_in[21];
  const float* head_b  = (const float*)d_in[22];
  const int* src = ei;
  const int* dst = ei + NE;
  float* out = (float*)d_out;

  // workspace (4B units). Aliasing: P = xw1' -> C.
  float* H     = (float*)d_ws;             // N*64
  float* P     = H + (size_t)NN * 64;      // N*64   xw1' then C
  float* Q     = P + (size_t)NN * 64;      // N*64   A
  float* XE    = Q + (size_t)NN * 64;      // NH*64  B
  float* DINV  = XE + (size_t)NH * 64;     // N
  float* TP    = DINV + NN;                // N   t' = t*dinv
  float* SV    = TP + NN;                  // 192
  int* GCNT    = (int*)(SV + 192);         // NBUK
  int* GBASE   = GCNT + NBUK;              // NBUK+1
  int* GCUR    = GBASE + NBUK + 1;         // NBUK
  int* OFF     = GCUR + NBUK;              // NS+1
  int* ADJ     = OFF + NS + 1;             // TOT
  // total ~95 MiB

  hipMemsetAsync(GCNT, 0, NBUK * 4, stream);

  k_vecs<<<1, 64, 0, stream>>>(conv2_W, conv2_b, cls_W, cls_b, lp_W, lp_b, head_W, head_b, SV);

  // CSR build (LDS-binned counting sort)
  k_ccount<<<512, 256, 0, stream>>>(dst, he, hv, GCNT);
  k_cscan<<<1, 1024, 0, stream>>>(GCNT, GBASE, GCUR);
  k_phase1<<<NWG1, 1024, 0, stream>>>(src, dst, he, hv, GCUR, ADJ);
  k_phase2<<<NBUK, 256, 0, stream>>>(GBASE, ADJ, OFF);
  k_dinv<<<(NN + 255) / 256, 256, 0, stream>>>(OFF, DINV);

  // dense: xw1' = (x @ conv1_W) * dinv[row]; h = relu(x @ lin_W + lin_b)
  k_gemm<128, false, false, true><<<2048, 256, 0, stream>>>(x, conv1_W, nullptr, DINV, P, NN);
  k_gemm<128, true, true, false><<<2048, 256, 0, stream>>>(x, lin_W, lin_b, nullptr, H, NN);

  // GCN branch collapsed to t' (conv2 folded into k_final)
  k_gcn1_gather<<<NN / 4, 256, 0, stream>>>(OFF, ADJ, P, DINV, conv1_b, SV, TP);

  // hyper branch dense parts: A = h @ W2[:64] (Q), C = h @ W1 + b1 (P)
  k_gemm<64, false, false, false><<<2048, 256, 0, stream>>>(H, W2, nullptr, nullptr, Q, NN);
  k_gemm<64, true, false, false><<<2048, 256, 0, stream>>>(H, W1, b1, nullptr, P, NN);

  // 16 hyperedges per wave -> 3125 waves -> 782 blocks
  k_xe_gather<<<782, 256, 0, stream>>>(OFF, ADJ, P, W2, b2, XE);

  // 16 nodes per wave -> 6250 waves -> 1563 blocks
  k_final<<<1563, 256, 0, stream>>>(OFF, ADJ, Q, XE, H, TP, DINV, Wu, bu, SV, out);
}